// Round 7
// baseline (431.578 us; speedup 1.0000x reference)
//
#include <hip/hip_runtime.h>
#include <hip/hip_bf16.h>

// x[32768,256] f32, W[256,256], b[256], emb[1024,256]
// d_out: quant[32768*256] | indices[32768] (as float) | loss[1]
//
// Pipeline:
//   k_prep    : ee[n]; emb -> e1,e2 (bf16 2-way split); W -> w1,w2,w3
//               (bf16 3-way split); zero flag counter. All in d_ws.
//   k_proj    : z = x @ W^T + b via 3-way-split bf16 MFMA (W splits
//               precomputed; x split on the fly). err ~1e-7.
//   k_screen  : split bf16 MFMA distance screen (z1e1+z1e2+z2e1, dot err
//               <= ~1.2e-6 worst case). Writes idx, or idx+4096 if top-2
//               gap < B_S = 1e-4 (> 4E + 2 ulp(256) -> unflagged winner is
//               provably the reference argmin incl. tie cases).
//   k_compact : device-wide ballot/atomic compaction of flagged tokens.
//   k_rescore : exact fp32 full 1024-code re-argmin, 4 tokens/block over
//               the global list; coalesced emb reads; round-2-proven
//               formula u = fl(zz+ee[n]); s = fma(-2,dot,u); first-index
//               ties (ascending-n per lane + lexicographic reduce).
//   k_gather  : quant = emb[idx] (in-place over z), loss partials
//   k_loss    : 1.25 * sum / (T*D)
#define TT 32768
#define DD 256
#define KK 1024
#define B_S 1e-4f

typedef __attribute__((ext_vector_type(8)))  short bf16x8;
typedef __attribute__((ext_vector_type(4)))  short bf16x4s;
typedef __attribute__((ext_vector_type(16))) float f32x16;

static inline __device__ short f2bf(float v) {
    __hip_bfloat16 h = __float2bfloat16(v);
    return __builtin_bit_cast(short, h);
}
static inline __device__ float bf2f(short s) {
    __hip_bfloat16 h = __builtin_bit_cast(__hip_bfloat16, s);
    return __bfloat162float(h);
}

// ---- workspace layout (bytes) ----
#define WS_EE    0          // 1024 f32
#define WS_PART  4096       // 256 f32
#define WS_CNT   5120       // 1 int
#define WS_LIST  5184       // 32768 int
#define WS_E1    136320     // 1024*256 bf16
#define WS_E2    660608
#define WS_W1    1184896    // 256*256 bf16
#define WS_W2    1315968
#define WS_W3    1447040    // ends 1578112 (~1.51 MB)

// ---------------------------------------------------------------------------
// Prep: ee + emb 2-way split (blocks 0..15), W 3-way split (blocks 16..19).
__global__ void k_prep(const float* __restrict__ emb, const float* __restrict__ W,
                       char* __restrict__ ws) {
    const int tid = threadIdx.x, b = blockIdx.x;
    float* ee  = (float*)(ws + WS_EE);
    short* e1g = (short*)(ws + WS_E1);
    short* e2g = (short*)(ws + WS_E2);
    short* w1g = (short*)(ws + WS_W1);
    short* w2g = (short*)(ws + WS_W2);
    short* w3g = (short*)(ws + WS_W3);
    if (b == 0 && tid == 0) *(int*)(ws + WS_CNT) = 0;

    if (b < 16) {
        int slot = b * 256 + tid;            // 0..4095
        int row = slot >> 2, qtr = slot & 3;
        const float* src = emb + (size_t)row * DD + qtr * 64;
        short* d1 = e1g + (size_t)row * DD + qtr * 64;
        short* d2 = e2g + (size_t)row * DD + qtr * 64;
        float ssq = 0.f;
#pragma unroll
        for (int i = 0; i < 16; ++i) {
            float4 v = *(const float4*)(src + i * 4);
            ssq += v.x * v.x + v.y * v.y + v.z * v.z + v.w * v.w;
            float e[4] = {v.x, v.y, v.z, v.w};
            bf16x4s s1, s2;
#pragma unroll
            for (int q = 0; q < 4; ++q) {
                short h1 = f2bf(e[q]); float r1 = e[q] - bf2f(h1);
                s1[q] = h1; s2[q] = f2bf(r1);
            }
            *(bf16x4s*)(d1 + i * 4) = s1;
            *(bf16x4s*)(d2 + i * 4) = s2;
        }
        ssq += __shfl_xor(ssq, 1);
        ssq += __shfl_xor(ssq, 2);
        if (qtr == 0) ee[row] = ssq;
    } else {
        int slot = (b - 16) * 256 + tid;     // 0..1023
        int row = slot >> 2, qtr = slot & 3;
        const float* src = W + (size_t)row * DD + qtr * 64;
        short* d1 = w1g + (size_t)row * DD + qtr * 64;
        short* d2 = w2g + (size_t)row * DD + qtr * 64;
        short* d3 = w3g + (size_t)row * DD + qtr * 64;
#pragma unroll
        for (int i = 0; i < 16; ++i) {
            float4 v = *(const float4*)(src + i * 4);
            float e[4] = {v.x, v.y, v.z, v.w};
            bf16x4s s1, s2, s3;
#pragma unroll
            for (int q = 0; q < 4; ++q) {
                short h1 = f2bf(e[q]); float r1 = e[q] - bf2f(h1);
                short h2 = f2bf(r1);   float r2 = r1 - bf2f(h2);
                s1[q] = h1; s2[q] = h2; s3[q] = f2bf(r2);
            }
            *(bf16x4s*)(d1 + i * 4) = s1;
            *(bf16x4s*)(d2 + i * 4) = s2;
            *(bf16x4s*)(d3 + i * 4) = s3;
        }
    }
}

// ---------------------------------------------------------------------------
// z = x @ W^T + b via 3-way split bf16 MFMA, W splits precomputed.
#define PW 40

__launch_bounds__(256, 2)
__global__ void k_proj(const float* __restrict__ x, const char* __restrict__ ws,
                       const float* __restrict__ bias, float* __restrict__ z) {
    __shared__ __align__(16) short Ax[3][64 * PW];    // 15 KB
    __shared__ __align__(16) short Bw[3][256 * PW];   // 60 KB
    const short* w1g = (const short*)(ws + WS_W1);
    const short* w2g = (const short*)(ws + WS_W2);
    const short* w3g = (const short*)(ws + WS_W3);
    const int tid = threadIdx.x;
    const int w = tid >> 6, lane = tid & 63;
    const int l31 = lane & 31, h = lane >> 5;
    const int t0 = blockIdx.x * 64;
    const int wt = (w & 1) * 32;
    const int wc = (w >> 1) * 128;

    f32x16 acc[4];
#pragma unroll
    for (int cb = 0; cb < 4; ++cb)
#pragma unroll
        for (int r = 0; r < 16; ++r) acc[cb][r] = 0.f;

    for (int kb = 0; kb < DD; kb += 32) {
        __syncthreads();
        // x tile 64x32 -> 3-way split on the fly
#pragma unroll
        for (int j = 0; j < 2; ++j) {
            int idx = j * 256 + tid, row = idx >> 3, c4 = idx & 7;
            float4 v = *(const float4*)(x + (size_t)(t0 + row) * DD + kb + c4 * 4);
            float e[4] = {v.x, v.y, v.z, v.w};
            bf16x4s s1, s2, s3;
#pragma unroll
            for (int q = 0; q < 4; ++q) {
                short h1 = f2bf(e[q]); float r1 = e[q] - bf2f(h1);
                short h2 = f2bf(r1);   float r2 = r1 - bf2f(h2);
                s1[q] = h1; s2[q] = h2; s3[q] = f2bf(r2);
            }
            int a = row * PW + c4 * 4;
            *(bf16x4s*)&Ax[0][a] = s1; *(bf16x4s*)&Ax[1][a] = s2; *(bf16x4s*)&Ax[2][a] = s3;
        }
        // W tiles: direct bf16 copy of precomputed splits
#pragma unroll
        for (int j = 0; j < 4; ++j) {
            int idx = j * 256 + tid, row = idx >> 2, c8 = idx & 3;
            size_t g = (size_t)row * DD + kb + c8 * 8;
            int a = row * PW + c8 * 8;
            *(bf16x8*)&Bw[0][a] = *(const bf16x8*)(w1g + g);
            *(bf16x8*)&Bw[1][a] = *(const bf16x8*)(w2g + g);
            *(bf16x8*)&Bw[2][a] = *(const bf16x8*)(w3g + g);
        }
        __syncthreads();
#pragma unroll
        for (int ks = 0; ks < 2; ++ks) {
            int ao = (wt + l31) * PW + ks * 16 + h * 8;
            bf16x8 a1 = *(bf16x8*)&Ax[0][ao];
            bf16x8 a2 = *(bf16x8*)&Ax[1][ao];
            bf16x8 a3 = *(bf16x8*)&Ax[2][ao];
#pragma unroll
            for (int cb = 0; cb < 4; ++cb) {
                int bo = (wc + cb * 32 + l31) * PW + ks * 16 + h * 8;
                bf16x8 b1 = *(bf16x8*)&Bw[0][bo];
                bf16x8 b2 = *(bf16x8*)&Bw[1][bo];
                bf16x8 b3 = *(bf16x8*)&Bw[2][bo];
                acc[cb] = __builtin_amdgcn_mfma_f32_32x32x16_bf16(a1, b3, acc[cb], 0, 0, 0);
                acc[cb] = __builtin_amdgcn_mfma_f32_32x32x16_bf16(a2, b2, acc[cb], 0, 0, 0);
                acc[cb] = __builtin_amdgcn_mfma_f32_32x32x16_bf16(a3, b1, acc[cb], 0, 0, 0);
                acc[cb] = __builtin_amdgcn_mfma_f32_32x32x16_bf16(a1, b2, acc[cb], 0, 0, 0);
                acc[cb] = __builtin_amdgcn_mfma_f32_32x32x16_bf16(a2, b1, acc[cb], 0, 0, 0);
                acc[cb] = __builtin_amdgcn_mfma_f32_32x32x16_bf16(a1, b1, acc[cb], 0, 0, 0);
            }
        }
    }
#pragma unroll
    for (int cb = 0; cb < 4; ++cb) {
        int col = wc + cb * 32 + l31;
        float bc = bias[col];
#pragma unroll
        for (int r = 0; r < 16; ++r) {
            int row = (r & 3) + 8 * (r >> 2) + 4 * h;
            z[(size_t)(t0 + wt + row) * DD + col] = acc[cb][r] + bc;
        }
    }
}

// ---------------------------------------------------------------------------
// Split bf16 MFMA screening: dot ~= z1e1 + z1e2 + z2e1 (err <= ~1.2e-6).
#define SW 264
#define BW 40

__launch_bounds__(256, 1)
__global__ void k_screen(const float* __restrict__ z, const char* __restrict__ ws,
                         float* __restrict__ out_idx) {
    __shared__ __align__(16) short A1[64 * SW];
    __shared__ __align__(16) short A2[64 * SW];
    __shared__ __align__(16) short B1[128 * BW];
    __shared__ __align__(16) short B2[128 * BW];
    __shared__ float ee_s[1024];
    __shared__ float zzs[64];
    __shared__ float r_bv[64]; __shared__ int r_bi[64]; __shared__ float r_sv[64];

    const float* ee_g = (const float*)(ws + WS_EE);
    const short* e1g  = (const short*)(ws + WS_E1);
    const short* e2g  = (const short*)(ws + WS_E2);

    const int tid = threadIdx.x;
    const int w = tid >> 6, lane = tid & 63;
    const int l31 = lane & 31, h = lane >> 5;
    const int t0 = blockIdx.x * 64;
    const int wr = (w >> 1) * 32, wc = (w & 1) * 64;

#pragma unroll
    for (int i = 0; i < 4; ++i) ee_s[i * 256 + tid] = ee_g[i * 256 + tid];

    // A init: z tile -> 2-way bf16 split in LDS + exact fp32 zz sums
#pragma unroll
    for (int i = 0; i < 16; ++i) {
        int tl = i * 4 + w;
        float4 v = *(const float4*)(z + (size_t)(t0 + tl) * DD + lane * 4);
        float sq = v.x * v.x + v.y * v.y + v.z * v.z + v.w * v.w;
#pragma unroll
        for (int o = 32; o; o >>= 1) sq += __shfl_xor(sq, o);
        if (lane == 0) zzs[tl] = sq;
        float e[4] = {v.x, v.y, v.z, v.w};
        bf16x4s s1, s2;
#pragma unroll
        for (int q = 0; q < 4; ++q) {
            short h1 = f2bf(e[q]); float r1 = e[q] - bf2f(h1);
            s1[q] = h1; s2[q] = f2bf(r1);
        }
        *(bf16x4s*)&A1[tl * SW + lane * 4] = s1;
        *(bf16x4s*)&A2[tl * SW + lane * 4] = s2;
    }

    float bestv[16], secv[16]; int besti[16];
#pragma unroll
    for (int r = 0; r < 16; ++r) { bestv[r] = 1e30f; secv[r] = 1e30f; besti[r] = 0; }

    bf16x8 p1[2], p2[2];
#pragma unroll
    for (int j = 0; j < 2; ++j) {
        int idx = j * 256 + tid, n_loc = idx >> 2, c8 = idx & 3;
        size_t g = (size_t)n_loc * DD + c8 * 8;
        p1[j] = *(const bf16x8*)(e1g + g);
        p2[j] = *(const bf16x8*)(e2g + g);
    }
    __syncthreads();

    for (int nc = 0; nc < 8; ++nc) {
        f32x16 acc0, acc1;
#pragma unroll
        for (int r = 0; r < 16; ++r) { acc0[r] = 0.f; acc1[r] = 0.f; }

        for (int kbi = 0; kbi < 8; ++kbi) {
            __syncthreads();
#pragma unroll
            for (int j = 0; j < 2; ++j) {
                int idx = j * 256 + tid, n_loc = idx >> 2, c8 = idx & 3;
                int a = n_loc * BW + c8 * 8;
                *(bf16x8*)&B1[a] = p1[j];
                *(bf16x8*)&B2[a] = p2[j];
            }
            __syncthreads();
            {   // prefetch next tile
                int rr = nc * 8 + kbi; int nrr = rr < 63 ? rr + 1 : 63;
                int nnc = nrr >> 3, nkbi = nrr & 7;
#pragma unroll
                for (int j = 0; j < 2; ++j) {
                    int idx = j * 256 + tid, n_loc = idx >> 2, c8 = idx & 3;
                    size_t g = (size_t)(nnc * 128 + n_loc) * DD + nkbi * 32 + c8 * 8;
                    p1[j] = *(const bf16x8*)(e1g + g);
                    p2[j] = *(const bf16x8*)(e2g + g);
                }
            }
#pragma unroll
            for (int ks = 0; ks < 2; ++ks) {
                int ao = (wr + l31) * SW + kbi * 32 + ks * 16 + h * 8;
                bf16x8 a1 = *(bf16x8*)&A1[ao];
                bf16x8 a2 = *(bf16x8*)&A2[ao];
                int bo0 = (wc + l31) * BW + ks * 16 + h * 8;
                int bo1 = (wc + 32 + l31) * BW + ks * 16 + h * 8;
                bf16x8 b1a = *(bf16x8*)&B1[bo0];
                bf16x8 b2a = *(bf16x8*)&B2[bo0];
                bf16x8 b1b = *(bf16x8*)&B1[bo1];
                bf16x8 b2b = *(bf16x8*)&B2[bo1];
                acc0 = __builtin_amdgcn_mfma_f32_32x32x16_bf16(a1, b2a, acc0, 0, 0, 0);
                acc0 = __builtin_amdgcn_mfma_f32_32x32x16_bf16(a2, b1a, acc0, 0, 0, 0);
                acc0 = __builtin_amdgcn_mfma_f32_32x32x16_bf16(a1, b1a, acc0, 0, 0, 0);
                acc1 = __builtin_amdgcn_mfma_f32_32x32x16_bf16(a1, b2b, acc1, 0, 0, 0);
                acc1 = __builtin_amdgcn_mfma_f32_32x32x16_bf16(a2, b1b, acc1, 0, 0, 0);
                acc1 = __builtin_amdgcn_mfma_f32_32x32x16_bf16(a1, b1b, acc1, 0, 0, 0);
            }
        }
#pragma unroll
        for (int j = 0; j < 2; ++j) {
            int n = nc * 128 + wc + j * 32 + l31;
            float en = ee_s[n];
#pragma unroll
            for (int r = 0; r < 16; ++r) {
                int row = (r & 3) + 8 * (r >> 2) + 4 * h;
                float u = zzs[wr + row] + en;
                float d = (j == 0) ? acc0[r] : acc1[r];
                float s = fmaf(-2.f, d, u);
                if (s < bestv[r])      { secv[r] = bestv[r]; bestv[r] = s; besti[r] = n; }
                else if (s < secv[r])  { secv[r] = s; }
            }
        }
    }

#pragma unroll
    for (int o = 1; o < 32; o <<= 1) {
#pragma unroll
        for (int r = 0; r < 16; ++r) {
            float ov = __shfl_xor(bestv[r], o);
            int   oi = __shfl_xor(besti[r], o);
            float os = __shfl_xor(secv[r], o);
            float mx = fmaxf(bestv[r], ov);
            secv[r] = fminf(fminf(secv[r], os), mx);
            if (ov < bestv[r] || (ov == bestv[r] && oi < besti[r])) { bestv[r] = ov; besti[r] = oi; }
        }
    }
    if ((w & 1) == 0 && l31 == 0) {
#pragma unroll
        for (int r = 0; r < 16; ++r) {
            int tr = wr + (r & 3) + 8 * (r >> 2) + 4 * h;
            r_bv[tr] = bestv[r]; r_bi[tr] = besti[r]; r_sv[tr] = secv[r];
        }
    }
    __syncthreads();
    if ((w & 1) == 1 && l31 == 0) {
#pragma unroll
        for (int r = 0; r < 16; ++r) {
            int tr = wr + (r & 3) + 8 * (r >> 2) + 4 * h;
            float lv = r_bv[tr]; int li = r_bi[tr]; float ls = r_sv[tr];
            float mx = fmaxf(lv, bestv[r]);
            float ns = fminf(fminf(ls, secv[r]), mx);
            float nv; int ni;
            if (bestv[r] < lv || (bestv[r] == lv && besti[r] < li)) { nv = bestv[r]; ni = besti[r]; }
            else { nv = lv; ni = li; }
            r_bv[tr] = nv; r_bi[tr] = ni; r_sv[tr] = ns;
        }
    }
    __syncthreads();
    if (tid < 64) {
        float flag = ((r_sv[tid] - r_bv[tid]) < B_S) ? 4096.0f : 0.0f;
        out_idx[t0 + tid] = (float)r_bi[tid] + flag;
    }
}

// ---------------------------------------------------------------------------
// Device-wide compaction of flagged tokens (wave ballot + one atomic/wave).
__global__ void k_compact(const float* __restrict__ out_idx, char* __restrict__ ws) {
    int* cnt  = (int*)(ws + WS_CNT);
    int* list = (int*)(ws + WS_LIST);
    const int t = blockIdx.x * 256 + threadIdx.x;
    const int lane = threadIdx.x & 63;
    bool fl = (out_idx[t] >= 4096.0f);
    unsigned long long m = __ballot(fl);
    int tot = (int)__popcll(m);
    int base = 0;
    if (lane == 0 && tot) base = atomicAdd(cnt, tot);
    base = __shfl(base, 0);
    if (fl) {
        int rank = (int)__popcll(m & ((1ull << lane) - 1ull));
        list[base + rank] = t;
    }
}

// ---------------------------------------------------------------------------
// Exact fp32 re-argmin over all 1024 codes, 4 tokens/block from global list.
__launch_bounds__(256, 4)
__global__ void k_rescore(const float* __restrict__ z, const float* __restrict__ emb,
                          const char* __restrict__ ws, float* __restrict__ out_idx) {
    __shared__ float zrows[4][260];
    __shared__ float zz4[4];
    __shared__ float fb_v[16][4]; __shared__ int fb_i[16][4];
    const float* ee_g = (const float*)(ws + WS_EE);
    const int* list   = (const int*)(ws + WS_LIST);
    const int M = *(const int*)(ws + WS_CNT);

    const int tid = threadIdx.x;
    const int w = tid >> 6, lane = tid & 63;
    const int qtr = lane >> 4, li = lane & 15;

    for (int base = blockIdx.x * 4; base < M; base += gridDim.x * 4) {
        const int nt = min(4, M - base);
        // stage: wave w loads token row w (coalesced), computes zz
        if (w < nt) {
            int t = list[base + w];
            float4 v = *(const float4*)(z + (size_t)t * DD + lane * 4);
            *(float4*)&zrows[w][lane * 4] = v;
            float s = v.x * v.x + v.y * v.y + v.z * v.z + v.w * v.w;
#pragma unroll
            for (int o = 32; o; o >>= 1) s += __shfl_xor(s, o);
            if (lane == 0) zz4[w] = s;
        } else {
            *(float4*)&zrows[w][lane * 4] = float4{0.f, 0.f, 0.f, 0.f};
            if (lane == 0) zz4[w] = 0.f;
        }
        __syncthreads();

        float bv[4]; int bi[4];
#pragma unroll
        for (int q = 0; q < 4; ++q) { bv[q] = 1e30f; bi[q] = 0; }
        for (int g = 0; g < 64; ++g) {
            int n = g * 16 + w * 4 + qtr;           // ascending n per lane
            const float* er = emb + (size_t)n * DD;
            float d[4] = {0.f, 0.f, 0.f, 0.f};
#pragma unroll
            for (int j = 0; j < 4; ++j) {
                float4 e = *(const float4*)(er + 64 * j + li * 4);
#pragma unroll
                for (int q = 0; q < 4; ++q) {
                    float4 zv = *(const float4*)&zrows[q][64 * j + li * 4];
                    d[q] = fmaf(e.x, zv.x, d[q]); d[q] = fmaf(e.y, zv.y, d[q]);
                    d[q] = fmaf(e.z, zv.z, d[q]); d[q] = fmaf(e.w, zv.w, d[q]);
                }
            }
#pragma unroll
            for (int o = 1; o < 16; o <<= 1) {
#pragma unroll
                for (int q = 0; q < 4; ++q) d[q] += __shfl_xor(d[q], o);
            }
            float en = ee_g[n];
#pragma unroll
            for (int q = 0; q < 4; ++q) {
                float u = zz4[q] + en;               // fl(zz+ee[n])
                float s = fmaf(-2.f, d[q], u);       // fl(u - 2*dot)
                if (s < bv[q]) { bv[q] = s; bi[q] = n; }
            }
        }
        if (li == 0) {
#pragma unroll
            for (int q = 0; q < 4; ++q) { fb_v[w * 4 + qtr][q] = bv[q]; fb_i[w * 4 + qtr][q] = bi[q]; }
        }
        __syncthreads();
        if (tid < nt) {
            float fv = fb_v[0][tid]; int fi = fb_i[0][tid];
#pragma unroll
            for (int s16 = 1; s16 < 16; ++s16) {
                float v = fb_v[s16][tid]; int i = fb_i[s16][tid];
                if (v < fv || (v == fv && i < fi)) { fv = v; fi = i; }
            }
            out_idx[list[base + tid]] = (float)fi;
        }
        __syncthreads();
    }
}

// ---------------------------------------------------------------------------
__global__ void k_gather(float* __restrict__ zq, const float* __restrict__ emb,
                         const float* __restrict__ out_idx, float* __restrict__ partial) {
    __shared__ float red[4];
    const int tid = threadIdx.x;
    const int t0 = blockIdx.x * 128;
    const int tl = tid >> 1, part = tid & 1;
    int widx = (int)out_idx[t0 + tl];
    widx = min(max(widx, 0), KK - 1);
    const float* erow = emb + (size_t)widx * DD;
    float* qrow = zq + (size_t)(t0 + tl) * DD;
    float lsum = 0.f;
#pragma unroll
    for (int k = 0; k < 32; ++k) {
        int f = part + 2 * k;
        float4 e  = *(const float4*)(erow + f * 4);
        float4 zv = *(const float4*)(qrow + f * 4);
        float dx = e.x - zv.x, dy = e.y - zv.y, dz = e.z - zv.z, dw = e.w - zv.w;
        lsum += dx * dx + dy * dy + dz * dz + dw * dw;
        *(float4*)(qrow + f * 4) = e;
    }
#pragma unroll
    for (int off = 32; off; off >>= 1) lsum += __shfl_down(lsum, off);
    if ((tid & 63) == 0) red[tid >> 6] = lsum;
    __syncthreads();
    if (tid == 0) partial[blockIdx.x] = red[0] + red[1] + red[2] + red[3];
}

// ---------------------------------------------------------------------------
__global__ void k_loss(const char* __restrict__ ws, float* __restrict__ out_loss) {
    __shared__ float red[4];
    const float* partial = (const float*)(ws + WS_PART);
    int tid = threadIdx.x;
    float s = partial[tid];
#pragma unroll
    for (int off = 32; off; off >>= 1) s += __shfl_down(s, off);
    if ((tid & 63) == 0) red[tid >> 6] = s;
    __syncthreads();
    if (tid == 0)
        out_loss[0] = (red[0] + red[1] + red[2] + red[3]) * (1.25f / 8388608.0f);
}

// ---------------------------------------------------------------------------
extern "C" void kernel_launch(void* const* d_in, const int* in_sizes, int n_in,
                              void* d_out, int out_size, void* d_ws, size_t ws_size,
                              hipStream_t stream) {
    const float* x   = (const float*)d_in[0];
    const float* W   = (const float*)d_in[1];
    const float* b   = (const float*)d_in[2];
    const float* emb = (const float*)d_in[3];

    float* out   = (float*)d_out;
    float* quant = out;                          // holds z, then quant
    float* oidx  = out + (size_t)TT * DD;
    float* oloss = oidx + TT;
    char*  ws    = (char*)d_ws;
    float* partial = (float*)(ws + WS_PART);

    k_prep   <<<20,       256, 0, stream>>>(emb, W, ws);
    k_proj   <<<TT / 64,  256, 0, stream>>>(x, ws, b, quant);
    k_screen <<<TT / 64,  256, 0, stream>>>(quant, ws, oidx);
    k_compact<<<TT / 256, 256, 0, stream>>>(oidx, ws);
    k_rescore<<<160,      256, 0, stream>>>(quant, emb, ws, oidx);
    k_gather <<<TT / 128, 256, 0, stream>>>(quant, emb, oidx, partial);
    k_loss   <<<1,        256, 0, stream>>>(ws, oloss);
}